// Round 7
// 1590.349 us; speedup vs baseline: 1.3122x; 1.3122x over previous
//
#include <hip/hip_runtime.h>

#define N_NODES 50000
#define N_EDGES 800000
#define DD 128

typedef __bf16 bf16x8 __attribute__((ext_vector_type(8)));
typedef float f32x4 __attribute__((ext_vector_type(4)));

// ---------------- workspace layout (bytes), total 282,033,472 (<= proven 282,033,664) ----------
static const size_t WT_OFF    = 0;          // 114688 bf16 transposed weights (229376 B)
static const size_t STATS_OFF = 229376;     // 1024 floats (4096 B)
static const size_t LAST_OFF  = 233472;     // 50000 ints (200000 B)
static const size_t HBF_OFF   = 433472;     // h as bf16, 12.8 MB — DEAD after k2_edge
static const size_t WSND_OFF  = 433472;     // w(n)=hp_send per node, f32 25.6 MB — overlaps hbf
static const size_t S_OFF     = 26033472;   // S(n)=seg-sum eta_new f32 25.6 MB; becomes aggP in place
static const size_t AGGH_OFF  = 51633472;   // aggH(n)=f(n)*S(n) f32 25.6 MB
static const size_t ETA_OFF   = 77233472;   // eta per edge, bf16 204.8 MB

// transposed-weight pack sub-offsets (elements). layout: Wt[n][k]
#define WLIN_T 0
#define WHPR_T 16384
#define WP2_T  49152
#define WHPS_T 65536
#define WP1_T  98304

// ---------------- helpers ----------------
__device__ __forceinline__ unsigned short f2bf(float x){
  unsigned u = __float_as_uint(x);
  u = (u + 0x7fffu + ((u >> 16) & 1u)) >> 16;
  return (unsigned short)u;
}
__device__ __forceinline__ unsigned packbf2(float a, float b){
  return (unsigned)f2bf(a) | ((unsigned)f2bf(b) << 16);
}
__device__ __forceinline__ float bf2f(unsigned short v){
  return __uint_as_float(((unsigned)v) << 16);
}

// MFMA over 8 col-tiles, K=128. Arow points at the lane's A row.
__device__ __forceinline__ void mfma_tile8(const unsigned short* Arow,
                                           const unsigned short* W,
                                           const int mm, const int q, f32x4* acc)
{
#pragma unroll
  for (int s = 0; s < 4; ++s){
    bf16x8 a = *(const bf16x8*)(Arow + s*32 + q*8);
#pragma unroll
    for (int c = 0; c < 8; ++c){
      bf16x8 b = *(const bf16x8*)(W + (c*16 + mm)*136 + s*32 + q*8);
      acc[c] = __builtin_amdgcn_mfma_f32_16x16x32_bf16(a, b, acc[c], 0, 0, 0);
    }
  }
}

// weight staging for 256-thread kernels: K=128 tile into W[128][136]
__device__ __forceinline__ void stage_w(const unsigned short* __restrict__ wt,
                                        unsigned short* __restrict__ W,
                                        int t, int base, int rstride)
{
  const int wrow = t >> 1, wpart = t & 1;
  const uint4* src = (const uint4*)(wt + base + wrow*rstride + wpart*64);
  uint4* dst = (uint4*)&W[wrow*136 + wpart*64];
#pragma unroll
  for (int j = 0; j < 8; ++j) dst[j] = src[j];
}

// ---------------- K0a: transpose weights to bf16 Wt[n][k] ----------------
__global__ __launch_bounds__(256) void k0a_weights(
    const float* __restrict__ Wlin, const float* __restrict__ Whpr,
    const float* __restrict__ Wp2,  const float* __restrict__ Whps,
    const float* __restrict__ Wp1,  unsigned short* __restrict__ wt)
{
  int i = blockIdx.x * 256 + threadIdx.x;
  if (i >= 114688) return;
  float v;
  if (i < 16384)      { int j = i;         int n = j >> 7, k = j & 127; v = Wlin[k*128 + n]; }
  else if (i < 49152) { int j = i - 16384; int n = j >> 8, k = j & 255; v = Whpr[k*128 + n]; }
  else if (i < 65536) { int j = i - 49152; int n = j >> 7, k = j & 127; v = Wp2 [k*128 + n]; }
  else if (i < 98304) { int j = i - 65536; int n = j >> 8, k = j & 255; v = Whps[k*128 + n]; }
  else                { int j = i - 98304; int n = j >> 7, k = j & 127; v = Wp1 [k*128 + n]; }
  wt[i] = f2bf(v);
}

// ---------------- K0b: h -> bf16 ----------------
__global__ __launch_bounds__(256) void k0b_cast(
    const float* __restrict__ h, unsigned short* __restrict__ hbf)
{
  int i = blockIdx.x * 256 + threadIdx.x;   // 1.6M threads, 4 floats each
  float4 v = ((const float4*)h)[i];
  uint2 o; o.x = packbf2(v.x, v.y); o.y = packbf2(v.z, v.w);
  ((uint2*)hbf)[i] = o;
}

// ---------------- K2: edge kernel — eta only ----------------
// eta = sigmoid((hs+hr+e)@Wlin + 3b); eta-stats; eta->global; S[rcv] += eta_new; lastE
struct SmemK2 {
  alignas(16) unsigned short X[128*136];   // hs+hr+e bf16; reused as eta dump
  alignas(16) unsigned short W[128*136];
  int   recIdx[128];
  float stat[256];
};

__global__ __launch_bounds__(512, 2) void k2_edge(
    const float* __restrict__ e,
    const int*   __restrict__ eidx,
    const float* __restrict__ b_lin,
    const unsigned short* __restrict__ hbf,
    const unsigned short* __restrict__ wt,
    unsigned short* __restrict__ etaOut,
    float* __restrict__ S,
    int*   __restrict__ lastE,
    float* __restrict__ gstats)
{
  __shared__ SmemK2 sm;
  const int t  = threadIdx.x;
  const int e0 = blockIdx.x * 128;
  const int row = t >> 2, part = t & 3;
  const int er  = e0 + row;
  const int snd = eidx[er];
  const int rcv = eidx[N_EDGES + er];
  if (part == 0){
    sm.recIdx[row] = rcv;
    atomicMax(&lastE[snd], er);
  }
  if (t < 256) sm.stat[t] = 0.f;

  // ---- stage X = hs + hr + e (bf16) ----
  {
    const uint4*  hs4 = (const uint4*)(hbf + (size_t)snd*DD + part*32);
    const uint4*  hr4 = (const uint4*)(hbf + (size_t)rcv*DD + part*32);
    const float4* ee4 = (const float4*)(e  + (size_t)er *DD + part*32);
    uint4* dX = (uint4*)&sm.X[row*136 + part*32];
#pragma unroll
    for (int j = 0; j < 4; ++j){
      uint4 a = hs4[j], b = hr4[j];
      float4 elo = ee4[2*j], ehi = ee4[2*j+1];
      uint4 o;
      o.x = packbf2(bf2f((unsigned short)(a.x & 0xffffu)) + bf2f((unsigned short)(b.x & 0xffffu)) + elo.x,
                    bf2f((unsigned short)(a.x >> 16))     + bf2f((unsigned short)(b.x >> 16))     + elo.y);
      o.y = packbf2(bf2f((unsigned short)(a.y & 0xffffu)) + bf2f((unsigned short)(b.y & 0xffffu)) + elo.z,
                    bf2f((unsigned short)(a.y >> 16))     + bf2f((unsigned short)(b.y >> 16))     + elo.w);
      o.z = packbf2(bf2f((unsigned short)(a.z & 0xffffu)) + bf2f((unsigned short)(b.z & 0xffffu)) + ehi.x,
                    bf2f((unsigned short)(a.z >> 16))     + bf2f((unsigned short)(b.z >> 16))     + ehi.y);
      o.w = packbf2(bf2f((unsigned short)(a.w & 0xffffu)) + bf2f((unsigned short)(b.w & 0xffffu)) + ehi.z,
                    bf2f((unsigned short)(a.w >> 16))     + bf2f((unsigned short)(b.w >> 16))     + ehi.w);
      dX[j] = o;
    }
  }
  // stage W_lin^T
  {
    const uint4* srcw = (const uint4*)(wt + WLIN_T + row*128 + part*32);
    uint4* dstw = (uint4*)&sm.W[row*136 + part*32];
#pragma unroll
    for (int j = 0; j < 4; ++j) dstw[j] = srcw[j];
  }
  __syncthreads();

  const int lane = t & 63;
  const int wv = t >> 6;
  const int mm = lane & 15;
  const int q  = lane >> 4;
  const int rw = wv * 16;

  f32x4 acc[8];
#pragma unroll
  for (int c = 0; c < 8; ++c) acc[c] = (f32x4){0.f,0.f,0.f,0.f};
  mfma_tile8(&sm.X[(rw+mm)*136], sm.W, mm, q, acc);

  float rs0=0.f, rs1=0.f, rs2=0.f, rs3=0.f;
#pragma unroll
  for (int c = 0; c < 8; ++c){
    float b3 = 3.f * b_lin[c*16 + mm];
#pragma unroll
    for (int g = 0; g < 4; ++g){
      float z = acc[c][g] + b3;
      acc[c][g] = 1.f / (1.f + __expf(-z));      // eta
    }
    rs0 += acc[c][0]; rs1 += acc[c][1]; rs2 += acc[c][2]; rs3 += acc[c][3];
  }
#pragma unroll
  for (int msk = 1; msk < 16; msk <<= 1){
    rs0 += __shfl_xor(rs0, msk); rs1 += __shfl_xor(rs1, msk);
    rs2 += __shfl_xor(rs2, msk); rs3 += __shfl_xor(rs3, msk);
  }
  const float inv0 = 1.f/rs0, inv1 = 1.f/rs1, inv2 = 1.f/rs2, inv3 = 1.f/rs3;

#pragma unroll
  for (int c = 0; c < 8; ++c){
    float s1 = acc[c][0] + acc[c][1] + acc[c][2] + acc[c][3];
    float s2 = acc[c][0]*acc[c][0] + acc[c][1]*acc[c][1] + acc[c][2]*acc[c][2] + acc[c][3]*acc[c][3];
    s1 += __shfl_xor(s1, 16); s1 += __shfl_xor(s1, 32);
    s2 += __shfl_xor(s2, 16); s2 += __shfl_xor(s2, 32);
    if (q == 0){
      atomicAdd(&sm.stat[c*16 + mm], s1);
      atomicAdd(&sm.stat[128 + c*16 + mm], s2);
    }
#pragma unroll
    for (int g = 0; g < 4; ++g)
      sm.X[(rw + q*4 + g)*136 + c*16 + mm] = f2bf(acc[c][g]);   // eta dump
  }
  __syncthreads();

  // ---- store eta to global ----
  {
    const uint4* srcX = (const uint4*)&sm.X[row*136 + part*32];
    uint4* dstE = (uint4*)(etaOut + (size_t)er*DD + part*32);
#pragma unroll
    for (int j = 0; j < 4; ++j) dstE[j] = srcX[j];
  }
  // ---- scatter S[rcv] += eta_new ----
  {
    const int r0 = sm.recIdx[rw + q*4 + 0];
    const int r1 = sm.recIdx[rw + q*4 + 1];
    const int r2 = sm.recIdx[rw + q*4 + 2];
    const int r3 = sm.recIdx[rw + q*4 + 3];
#pragma unroll
    for (int c = 0; c < 8; ++c){
      const int col = c*16 + mm;
      unsafeAtomicAdd(&S[(size_t)r0*DD + col], acc[c][0]*inv0);
      unsafeAtomicAdd(&S[(size_t)r1*DD + col], acc[c][1]*inv1);
      unsafeAtomicAdd(&S[(size_t)r2*DD + col], acc[c][2]*inv2);
      unsafeAtomicAdd(&S[(size_t)r3*DD + col], acc[c][3]*inv3);
    }
  }
  if (t < 256) unsafeAtomicAdd(&gstats[t], sm.stat[t]);   // [0..127]=sum_eta [128..255]=sumsq_eta
}

// ---------------- K2n: per-node GEMMs — w(n), aggH(n)=f(n)*S(n), aggP(n)=g(n)*S(n) ----------------
struct SmemK2n {
  alignas(16) unsigned short HP[64*280];   // [h | p] bf16, K=256
  alignas(16) unsigned short W [128*136];
};

__global__ __launch_bounds__(256, 2) void k2n_nodes(
    const float* __restrict__ h, const float* __restrict__ p,
    const unsigned short* __restrict__ wt,
    const float* __restrict__ b_hps, const float* __restrict__ b_hpr,
    const float* __restrict__ b_p2,
    float* __restrict__ S,          // in: seg-sum eta_new; out: aggP (in place)
    float* __restrict__ wbuf,       // out: w(n) = hp_send+bias
    float* __restrict__ aggH)       // out: f(n)*S(n)
{
  __shared__ SmemK2n sm;
  const int t = threadIdx.x;
  const int n0 = blockIdx.x * 64;
  const int row = t >> 2, part = t & 3;
  const int n = n0 + row;
  const int ncl = (n < N_NODES) ? n : (N_NODES - 1);
  {
    const float4* h4 = (const float4*)(h + (size_t)ncl*DD + part*32);
    const float4* p4 = (const float4*)(p + (size_t)ncl*DD + part*32);
    uint4* dH = (uint4*)&sm.HP[row*280 + part*32];
    uint4* dP = (uint4*)&sm.HP[row*280 + 128 + part*32];
#pragma unroll
    for (int j = 0; j < 4; ++j){
      float4 a = h4[2*j], b = h4[2*j+1];
      uint4 oh; oh.x = packbf2(a.x,a.y); oh.y = packbf2(a.z,a.w);
      oh.z = packbf2(b.x,b.y); oh.w = packbf2(b.z,b.w);
      dH[j] = oh;
      float4 cc = p4[2*j], d = p4[2*j+1];
      uint4 op; op.x = packbf2(cc.x,cc.y); op.y = packbf2(cc.z,cc.w);
      op.z = packbf2(d.x,d.y); op.w = packbf2(d.z,d.w);
      dP[j] = op;
    }
  }
  stage_w(wt, sm.W, t, WHPS_T, 256);
  __syncthreads();

  const int lane = t & 63, wv = t >> 6, mm = lane & 15, q = lane >> 4, rw = wv*16;
  f32x4 accA[8], accB[8];
#pragma unroll
  for (int c = 0; c < 8; ++c) accA[c] = (f32x4){0.f,0.f,0.f,0.f};
  mfma_tile8(&sm.HP[(rw+mm)*280], sm.W, mm, q, accA);           // h @ Whps[:128]
  __syncthreads();
  stage_w(wt, sm.W, t, WHPS_T + 128, 256);
  __syncthreads();
  mfma_tile8(&sm.HP[(rw+mm)*280 + 128], sm.W, mm, q, accA);     // p @ Whps[128:]

  // write w(n) = hp_send (with bias), f32
#pragma unroll
  for (int c = 0; c < 8; ++c){
    const int col = c*16 + mm;
    const float bh = b_hps[col];
#pragma unroll
    for (int g = 0; g < 4; ++g){
      const int nn = n0 + rw + q*4 + g;
      if (nn < N_NODES) wbuf[(size_t)nn*DD + col] = accA[c][g] + bh;
    }
  }
  __syncthreads();
  stage_w(wt, sm.W, t, WHPR_T, 256);
  __syncthreads();
#pragma unroll
  for (int c = 0; c < 8; ++c) accB[c] = (f32x4){0.f,0.f,0.f,0.f};
  mfma_tile8(&sm.HP[(rw+mm)*280], sm.W, mm, q, accB);           // h @ Whpr[:128]
  __syncthreads();
  stage_w(wt, sm.W, t, WHPR_T + 128, 256);
  __syncthreads();
  mfma_tile8(&sm.HP[(rw+mm)*280 + 128], sm.W, mm, q, accB);     // p @ Whpr[128:]
  __syncthreads();
  stage_w(wt, sm.W, t, WP2_T, 128);
  __syncthreads();
  f32x4 accC[8];
#pragma unroll
  for (int c = 0; c < 8; ++c) accC[c] = (f32x4){0.f,0.f,0.f,0.f};
  mfma_tile8(&sm.HP[(rw+mm)*280 + 128], sm.W, mm, q, accC);     // p @ Wp2

  // aggH = (f+b_hpr)*S ; aggP = (g+b_p2)*S (in place over S)
#pragma unroll
  for (int c = 0; c < 8; ++c){
    const int col = c*16 + mm;
    const float bhr = b_hpr[col], bp2 = b_p2[col];
#pragma unroll
    for (int g = 0; g < 4; ++g){
      const int nn = n0 + rw + q*4 + g;
      if (nn >= N_NODES) continue;
      const size_t off = (size_t)nn*DD + col;
      const float sv = S[off];
      aggH[off] = (accB[c][g] + bhr) * sv;
      S[off]    = (accC[c][g] + bp2) * sv;
    }
  }
}

// ---------------- K3s: BN stats for t(e) = w(snd(e)) + (e<N ? aggH[e] : 0) ----------------
__global__ __launch_bounds__(256) void k3_stats(
    const int* __restrict__ eidx,
    const float* __restrict__ wbuf, const float* __restrict__ aggH,
    float* __restrict__ gstats)
{
  __shared__ float st[256];
  const int t = threadIdx.x;
  st[t] = 0.f;
  __syncthreads();
  const int cg = (t & 31) * 4;             // 32 lanes x 4 cols = 128 cols
  const int rl = t >> 5;                   // 8 edge-rows per block-iter
  float s1[4] = {0.f,0.f,0.f,0.f};
  float s2[4] = {0.f,0.f,0.f,0.f};
  for (int i = blockIdx.x*8 + rl; i < N_EDGES; i += gridDim.x*8){
    const int sn = eidx[i];
    const float4 w = *(const float4*)(wbuf + (size_t)sn*DD + cg);
    float tv[4] = {w.x, w.y, w.z, w.w};
    if (i < N_NODES){
      const float4 a = *(const float4*)(aggH + (size_t)i*DD + cg);
      tv[0] += a.x; tv[1] += a.y; tv[2] += a.z; tv[3] += a.w;
    }
#pragma unroll
    for (int j = 0; j < 4; ++j){
      s1[j] += tv[j];
      s2[j] += tv[j]*tv[j];
    }
  }
#pragma unroll
  for (int j = 0; j < 4; ++j){
    atomicAdd(&st[cg + j], s1[j]);
    atomicAdd(&st[128 + cg + j], s2[j]);
  }
  __syncthreads();
  unsafeAtomicAdd(&gstats[256 + t], st[t]);   // [256..383]=sum_t [384..511]=sumsq_t
}

// ---------------- K4: finalize BN stats ----------------
__global__ void k4_finalize(float* __restrict__ gs)
{
  const int d = threadIdx.x;  // 128
  const float invE = 1.f / (float)N_EDGES;
  float m1 = gs[d] * invE;
  float v1 = gs[128 + d] * invE - m1*m1;
  gs[512 + d] = m1; gs[640 + d] = rsqrtf(v1 + 1e-5f);
  float m2 = gs[256 + d] * invE;
  float v2 = gs[384 + d] * invE - m2*m2;
  gs[768 + d] = m2; gs[896 + d] = rsqrtf(v2 + 1e-5f);
}

// ---------------- K5: e_out = e + relu(bn(eta)) ----------------
__global__ __launch_bounds__(256) void k5_eout(
    const float* __restrict__ e, const unsigned short* __restrict__ eta,
    const float* __restrict__ gs, const float* __restrict__ gamma,
    const float* __restrict__ beta, float* __restrict__ eout)
{
  __shared__ float sg[128], sb[128], smu[128], srs[128];
  const int t = threadIdx.x;
  if (t < 128){ sg[t] = gamma[t]; sb[t] = beta[t]; }
  else { int d = t - 128; smu[d] = gs[512 + d]; srs[d] = gs[640 + d]; }
  __syncthreads();
  const size_t idx = (size_t)blockIdx.x * 256 + t;
  const int r  = (int)(idx >> 4);
  const int c0 = (int)(idx & 15) * 8;
  const float4* ein = (const float4*)(e + (size_t)r*DD + c0);
  const uint4 u = *(const uint4*)(eta + (size_t)r*DD + c0);
  float4 lo = ein[0], hi = ein[1];
  float ev[8] = {
    bf2f((unsigned short)(u.x & 0xffffu)), bf2f((unsigned short)(u.x >> 16)),
    bf2f((unsigned short)(u.y & 0xffffu)), bf2f((unsigned short)(u.y >> 16)),
    bf2f((unsigned short)(u.z & 0xffffu)), bf2f((unsigned short)(u.z >> 16)),
    bf2f((unsigned short)(u.w & 0xffffu)), bf2f((unsigned short)(u.w >> 16))};
  float ef[8] = {lo.x, lo.y, lo.z, lo.w, hi.x, hi.y, hi.z, hi.w};
  float o[8];
#pragma unroll
  for (int j = 0; j < 8; ++j){
    const int d = c0 + j;
    o[j] = ef[j] + fmaxf(0.f, sg[d]*(ev[j] - smu[d])*srs[d] + sb[d]);
  }
  float4* out = (float4*)(eout + (size_t)r*DD + c0);
  out[0] = (float4){o[0],o[1],o[2],o[3]};
  out[1] = (float4){o[4],o[5],o[6],o[7]};
}

// ---------------- K6: per-node h_out, p_out ----------------
struct SmemK6 {
  alignas(16) unsigned short P[64*136];
  alignas(16) unsigned short W[128*136];
};

__global__ __launch_bounds__(256, 2) void k6_nodes(
    const float* __restrict__ h, const float* __restrict__ p,
    const unsigned short* __restrict__ wt,
    const float* __restrict__ wbuf,
    const float* __restrict__ aggH, const float* __restrict__ aggP,
    const int* __restrict__ lastE, const float* __restrict__ gs,
    const float* __restrict__ b_p1,
    const float* __restrict__ gamma, const float* __restrict__ beta,
    float* __restrict__ hout, float* __restrict__ pout)
{
  __shared__ SmemK6 sm;
  const int t = threadIdx.x;
  const int n0 = blockIdx.x * 64;
  const int row = t >> 2, part = t & 3;
  const int n = n0 + row;
  const int ncl = (n < N_NODES) ? n : (N_NODES - 1);
  {
    const float4* p4 = (const float4*)(p + (size_t)ncl*DD + part*32);
    uint4* dP = (uint4*)&sm.P[row*136 + part*32];
#pragma unroll
    for (int j = 0; j < 4; ++j){
      float4 a = p4[2*j], b = p4[2*j+1];
      uint4 op; op.x = packbf2(a.x,a.y); op.y = packbf2(a.z,a.w);
      op.z = packbf2(b.x,b.y); op.w = packbf2(b.z,b.w);
      dP[j] = op;
    }
  }
  stage_w(wt, sm.W, t, WP1_T, 128);
  __syncthreads();

  const int lane = t & 63, wv = t >> 6, mm = lane & 15, q = lane >> 4, rw = wv*16;
  f32x4 accQ[8];
#pragma unroll
  for (int c = 0; c < 8; ++c) accQ[c] = (f32x4){0.f,0.f,0.f,0.f};
  mfma_tile8(&sm.P[(rw+mm)*136], sm.W, mm, q, accQ);            // p @ Wp1

  int ie[4];
#pragma unroll
  for (int g = 0; g < 4; ++g){
    const int rr = n0 + rw + q*4 + g;
    ie[g] = (rr < N_NODES) ? lastE[rr] : -1;
  }
#pragma unroll
  for (int c = 0; c < 8; ++c){
    const int col = c*16 + mm;
    const float bp = b_p1[col];
    const float ga = gamma[col], be = beta[col];
    const float mu = gs[768 + col], rstd = gs[896 + col];
#pragma unroll
    for (int g = 0; g < 4; ++g){
      const int nn = n0 + rw + q*4 + g;
      if (nn >= N_NODES) continue;
      const size_t off = (size_t)nn*DD + col;
      const float hn = h[off], pn = p[off];
      const int i = ie[g];
      float addh = 0.f, addp = 0.f;
      if (i >= 0){
        const float agh = (i < N_NODES) ? aggH[(size_t)i*DD + col] : 0.f;
        const float agp = (i < N_NODES) ? aggP[(size_t)i*DD + col] : 0.f;
        const float tv = wbuf[off] + agh;
        addh = fmaxf(0.f, ga*(tv - mu)*rstd + be);
        addp = tanhf(accQ[c][g] + bp + agp);
      }
      hout[off] = hn + addh;
      pout[off] = pn + addp;
    }
  }
}

// ---------------- launcher ----------------
extern "C" void kernel_launch(void* const* d_in, const int* in_sizes, int n_in,
                              void* d_out, int out_size, void* d_ws, size_t ws_size,
                              hipStream_t stream)
{
  const float* h     = (const float*)d_in[0];
  const float* e     = (const float*)d_in[1];
  const float* p     = (const float*)d_in[2];
  const int*   eidx  = (const int*)  d_in[3];
  const float* W_lin = (const float*)d_in[4];
  const float* b_lin = (const float*)d_in[5];
  const float* W_hps = (const float*)d_in[6];
  const float* b_hps = (const float*)d_in[7];
  const float* W_hpr = (const float*)d_in[8];
  const float* b_hpr = (const float*)d_in[9];
  const float* W_p1  = (const float*)d_in[10];
  const float* b_p1  = (const float*)d_in[11];
  const float* W_p2  = (const float*)d_in[12];
  const float* b_p2  = (const float*)d_in[13];
  const float* gamma = (const float*)d_in[14];
  const float* beta  = (const float*)d_in[15];

  char* ws = (char*)d_ws;
  unsigned short* wt    = (unsigned short*)(ws + WT_OFF);
  float*          gst   = (float*)(ws + STATS_OFF);
  int*            lastE = (int*)(ws + LAST_OFF);
  unsigned short* hbf   = (unsigned short*)(ws + HBF_OFF);
  float*          wbuf  = (float*)(ws + WSND_OFF);   // overlaps hbf (hbf dead after k2)
  float*          S     = (float*)(ws + S_OFF);      // becomes aggP in place
  float*          aggH  = (float*)(ws + AGGH_OFF);
  unsigned short* eta   = (unsigned short*)(ws + ETA_OFF);

  float* hout = (float*)d_out;
  float* eout = hout + (size_t)N_NODES * DD;
  float* pout = eout + (size_t)N_EDGES * DD;

  hipMemsetAsync(ws + STATS_OFF, 0, 4096, stream);
  hipMemsetAsync(ws + LAST_OFF, 0xFF, (size_t)N_NODES * 4, stream);
  hipMemsetAsync(ws + S_OFF, 0, (size_t)N_NODES * DD * 4, stream);

  k0a_weights<<<448, 256, 0, stream>>>(W_lin, W_hpr, W_p2, W_hps, W_p1, wt);
  k0b_cast   <<<6250, 256, 0, stream>>>(h, hbf);
  k2_edge    <<<6250, 512, 0, stream>>>(e, eidx, b_lin, hbf, wt, eta, S, lastE, gst);
  k2n_nodes  <<<782, 256, 0, stream>>>(h, p, wt, b_hps, b_hpr, b_p2, S, wbuf, aggH);
  k3_stats   <<<512, 256, 0, stream>>>(eidx, wbuf, aggH, gst);
  k4_finalize<<<1, 128, 0, stream>>>(gst);
  k5_eout    <<<50000, 256, 0, stream>>>(e, eta, gst, gamma, beta, eout);
  k6_nodes   <<<782, 256, 0, stream>>>(h, p, wt, wbuf, aggH, S, lastE, gst,
                                       b_p1, gamma, beta, hout, pout);
}